// Round 18
// baseline (394.866 us; speedup 1.0000x reference)
//
#include <hip/hip_runtime.h>
#include <hip/hip_bf16.h>

// PermutationGenerator: B=8192, N=64, D=128, LATENT=256, TEMP=0.1, 20 Sinkhorn iters.
// d_in (ALL f32): [0] padded [B][64][128], [1] set_size int32 [B], [2] maskB (UNUSED),
//       [3] gumbel [B][64][64], [4] W1 [128][256], [5] b1 [256],
//       [6] W2 [256][64], [7] b2 [64]
// d_out f32: [0:8192] set_size, then permuted [B][64][128].
//
// R18: kernel A goes LDS-FREE — x fragments live in registers.
//   Evidence: A pinned at ~213us across 3 structures (R13/R16/R17), all pipes
//   idle => per-wave serial chain bound. R17's x-LDS path is ~8-way bank
//   conflicted (8.9e6) and adds write->read latency to every GEMM1' B-frag.
//   The B-frag global pattern x[16nr+lc][kk*32+8g..+8] is 32 fully-covered
//   64B lines per wave-instruction, so load the 16 frags ONCE into 64 VGPRs
//   at entry (R6's 952MB FETCH came from re-loading x per-lb, not from this
//   pattern). A now: zero LDS, zero barriers, one-shot x latency (T14).
//   Peak regs ~205 < 256; NO launch bound (R13 spill lesson).
// B: unchanged (R11-verified wave-per-batch sinkhorn+GEMM3, ~floor).

typedef _Float16 h16;
typedef h16 h8 __attribute__((ext_vector_type(8)));
typedef __fp16 fp16x2 __attribute__((ext_vector_type(2)));
typedef float v4f __attribute__((ext_vector_type(4)));

template<int CTRL>
__device__ __forceinline__ float dppf(float x) {
  return __int_as_float(__builtin_amdgcn_update_dpp(
      0, __float_as_int(x), CTRL, 0xF, 0xF, true));
}
__device__ __forceinline__ float red16_sum(float x) {
  x += dppf<0xB1>(x);
  x += dppf<0x4E>(x);
  x += dppf<0x124>(x);
  x += dppf<0x128>(x);
  return x;
}
__device__ __forceinline__ float frcp(float x) { return __builtin_amdgcn_rcpf(x); }
__device__ __forceinline__ float bperm(int addr, float v) {
  return __int_as_float(__builtin_amdgcn_ds_bpermute(addr, __float_as_int(v)));
}
__device__ __forceinline__ h8 cvt8(v4f a, v4f b) {
  union { h8 v; fp16x2 p[4]; } u;
  u.p[0] = __builtin_amdgcn_cvt_pkrtz(a[0], a[1]);
  u.p[1] = __builtin_amdgcn_cvt_pkrtz(a[2], a[3]);
  u.p[2] = __builtin_amdgcn_cvt_pkrtz(b[0], b[1]);
  u.p[3] = __builtin_amdgcn_cvt_pkrtz(b[2], b[3]);
  return u.v;
}

// w1s[kk*8192 + col*32 + e] = W1[(kk*32+e)*256 + col]   (kk<4, col<256, e<32)
// w2s[kk*2048 + j*32 + e]   = W2[(kk*32+e)*64 + j]      (kk<8, j<64,  e<32)
__global__ __launch_bounds__(256) void prep_w(const float* __restrict__ W1,
                                              const float* __restrict__ W2,
                                              h16* __restrict__ w1s,
                                              h16* __restrict__ w2s) {
  int t = blockIdx.x * 256 + threadIdx.x;
  if (t < 128 * 256) {
    int row = t >> 8, col = t & 255;          // W1[row][col]
    int kk = row >> 5, e = row & 31;
    w1s[kk * 8192 + col * 32 + e] = (h16)W1[t];
  } else if (t < 128 * 256 + 256 * 64) {
    int t2 = t - 128 * 256;
    int row = t2 >> 6, j = t2 & 63;           // W2[row][j]
    int kk = row >> 5, e = row & 31;
    w2s[kk * 2048 + j * 32 + e] = (h16)W2[t2];
  }
}

// ============ Kernel A: wave-per-batch MLP + init, LDS-FREE, zero barriers ===
template<bool WSF>
__global__ __launch_bounds__(64) void mlp_init_wave(
    const float* __restrict__ xf,
    const int* __restrict__ ssz,
    const float* __restrict__ gn,
    const float* __restrict__ b1,
    const float* __restrict__ b2,
    const h16* __restrict__ w1s,   // == W1^T coalesced: [kk<4][lat<256][e<32]
    const h16* __restrict__ w2s,   // == W2^T coalesced: [kk<8][j<64][e<32]
    const float* __restrict__ W1f,
    const float* __restrict__ W2f,
    float* __restrict__ outp) {
  const int lane = threadIdx.x;
  const int g = lane >> 4, lc = lane & 15;
  const int b = blockIdx.x;
  const int k = ssz[b];
  const int mcnt = (k + 15) >> 4;
  const float* xb = xf + (size_t)b * 8192;

  // ---- x fragments ONCE into registers (T14 one-shot latency):
  //      bx[nr][kk][e] = x[16nr+lc][kk*32+8g+e]  (32 covered 64B lines/instr)
  h8 bx[4][4];
#pragma unroll
  for (int nr = 0; nr < 4; ++nr)
#pragma unroll
    for (int kk = 0; kk < 4; ++kk) {
      const float* px = xb + (16 * nr + lc) * 128 + kk * 32 + 8 * g;
      bx[nr][kk] = cvt8(*(const v4f*)px, *(const v4f*)(px + 4));
    }

  // bpermute source lanes for h^T D-frag -> B-frag redistribution (R6-verified)
  const int srcA = ((2 * (g & 1)) * 16 + lc) * 4;  // elems 0..3
  const int srcB = srcA + 64;                      // elems 4..7

  // p[mj][nr][q] accumulates net^T: = net[r=16nr+lc][j=16mj+4g+q]
  v4f p[4][4];
#pragma unroll
  for (int mj = 0; mj < 4; ++mj)
#pragma unroll
    for (int nr = 0; nr < 4; ++nr) p[mj][nr] = (v4f){0.f, 0.f, 0.f, 0.f};

  // ---- MLP: 8 slabs of 32 latents; GEMM1' from register-x + coalesced w1s;
  //      bpermute h^T; GEMM2' partial with coalesced w2s. (R6-verified flow)
#pragma unroll 1
  for (int lb = 0; lb < 8; ++lb) {
    v4f accT[2][4];
#pragma unroll
    for (int mt = 0; mt < 2; ++mt)
#pragma unroll
      for (int nr = 0; nr < 4; ++nr) accT[mt][nr] = (v4f){0.f, 0.f, 0.f, 0.f};

#pragma unroll
    for (int kk = 0; kk < 4; ++kk) {
      h8 aw[2];
#pragma unroll
      for (int mt = 0; mt < 2; ++mt) {
        if (WSF) {
          aw[mt] = *(const h8*)&w1s[kk * 8192 + (lb * 32 + 16 * mt + lc) * 32 + 8 * g];
        } else {
          h8 t;
#pragma unroll
          for (int e = 0; e < 8; ++e)
            t[e] = (h16)W1f[(kk * 32 + 8 * g + e) * 256 + lb * 32 + 16 * mt + lc];
          aw[mt] = t;
        }
      }
#pragma unroll
      for (int nr = 0; nr < 4; ++nr)
        if (nr < mcnt) {
          accT[0][nr] = __builtin_amdgcn_mfma_f32_16x16x32_f16(aw[0], bx[nr][kk], accT[0][nr], 0, 0, 0);
          accT[1][nr] = __builtin_amdgcn_mfma_f32_16x16x32_f16(aw[1], bx[nr][kk], accT[1][nr], 0, 0, 0);
        }
    }

    // bias + relu -> h^T D-frags (ht[mt][nr][q] = h^T[lb*32+16mt+4g+q][16nr+lc])
    v4f b1a = *(const v4f*)&b1[lb * 32 + 4 * g];
    v4f b1b = *(const v4f*)&b1[lb * 32 + 16 + 4 * g];
    float ht0[4][4], ht1[4][4];
#pragma unroll
    for (int nr = 0; nr < 4; ++nr)
      if (nr < mcnt)
#pragma unroll
        for (int q = 0; q < 4; ++q) {
          ht0[nr][q] = fmaxf(accT[0][nr][q] + b1a[q], 0.0f);
          ht1[nr][q] = fmaxf(accT[1][nr][q] + b1b[q], 0.0f);
        }

    // GEMM2' partial: A = W2^T rows j (coalesced), B = h^T via bpermute
    h8 aj[4];
#pragma unroll
    for (int mj = 0; mj < 4; ++mj)
      if (mj < mcnt) {
        if (WSF) {
          aj[mj] = *(const h8*)&w2s[lb * 2048 + (16 * mj + lc) * 32 + 8 * g];
        } else {
          h8 t;
#pragma unroll
          for (int e = 0; e < 8; ++e)
            t[e] = (h16)W2f[(lb * 32 + 8 * g + e) * 64 + 16 * mj + lc];
          aj[mj] = t;
        }
      }
#pragma unroll
    for (int nr = 0; nr < 4; ++nr)
      if (nr < mcnt) {
        float hv[8];
#pragma unroll
        for (int e = 0; e < 8; ++e) {
          const int a_ = (e < 4) ? srcA : srcB;
          float v0 = bperm(a_, ht0[nr][e & 3]);
          float v1 = bperm(a_, ht1[nr][e & 3]);
          hv[e] = (g >= 2) ? v1 : v0;
        }
        h8 bh = cvt8((v4f){hv[0], hv[1], hv[2], hv[3]},
                     (v4f){hv[4], hv[5], hv[6], hv[7]});
#pragma unroll
        for (int mj = 0; mj < 4; ++mj)
          if (mj < mcnt)
            p[mj][nr] = __builtin_amdgcn_mfma_f32_16x16x32_f16(aj[mj], bh, p[mj][nr], 0, 0, 0);
      }
  }

  // ---- init (R6-verified): la = net^T + b2 + gn; mask; rowmax over j; exp2
  v4f b2j[4];
#pragma unroll
  for (int mj = 0; mj < 4; ++mj) b2j[mj] = *(const v4f*)&b2[16 * mj + 4 * g];

#pragma unroll
  for (int nr = 0; nr < 4; ++nr)
    if (nr < mcnt) {
      const int r = 16 * nr + lc;
#pragma unroll
      for (int mj = 0; mj < 4; ++mj)
        if (mj < mcnt) {
          v4f gv = *(const v4f*)(gn + (size_t)b * 4096 + r * 64 + 16 * mj + 4 * g);
#pragma unroll
          for (int q = 0; q < 4; ++q) {
            const int j = 16 * mj + 4 * g + q;
            const float la = p[mj][nr][q] + b2j[mj][q] + gv[q];
            p[mj][nr][q] = (r < k && j < k) ? la : -1e30f;
          }
        }
      float m_ = -1e30f;
#pragma unroll
      for (int mj = 0; mj < 4; ++mj)
        if (mj < mcnt)
#pragma unroll
          for (int q = 0; q < 4; ++q) m_ = fmaxf(m_, p[mj][nr][q]);
      m_ = fmaxf(m_, __shfl_xor(m_, 16));
      m_ = fmaxf(m_, __shfl_xor(m_, 32));
#pragma unroll
      for (int mj = 0; mj < 4; ++mj)
        if (mj < mcnt)
#pragma unroll
          for (int q = 0; q < 4; ++q) {
            const float la = p[mj][nr][q];
            p[mj][nr][q] = (la > -1e29f) ? exp2f((la - m_) * 14.4269504089f) : 0.0f;
          }
    } else {
#pragma unroll
      for (int mj = 0; mj < 4; ++mj) p[mj][nr] = (v4f){0.f, 0.f, 0.f, 0.f};
    }

  // masked (mj>=mcnt) exact zeros:
#pragma unroll
  for (int mj = 0; mj < 4; ++mj)
    if (mj >= mcnt)
#pragma unroll
      for (int nr = 0; nr < 4; ++nr) p[mj][nr] = (v4f){0.f, 0.f, 0.f, 0.f};

  // ---- store P0 directly in B's wave layout: v4f @ P0[(mj*4+nr)*256+lane*4]
  float* P0 = outp + 8192 + (size_t)b * 8192;
#pragma unroll
  for (int mj = 0; mj < 4; ++mj)
#pragma unroll
    for (int nr = 0; nr < 4; ++nr)
      *(v4f*)&P0[(mj * 4 + nr) * 256 + lane * 4] = p[mj][nr];
}

// ================= Kernel B: wave-per-batch Sinkhorn + GEMM3, ZERO barriers ==
// Per-wave private 8KB pth: P^T subtiled [i>>3][j][i&7] f16 (conflict-free b128)
__global__ __launch_bounds__(256, 4) void sink_out(
    const float* __restrict__ xf,
    const int* __restrict__ ssz,
    float* __restrict__ outp) {
  __shared__ h16 pth_all[4][4096];

  const int tid = threadIdx.x;
  const int w = tid >> 6, lane = tid & 63, g = lane >> 4, lc = lane & 15;
  h16* pth = pth_all[w];

  const int b = blockIdx.x * 4 + w;
  const int k = ssz[b];
  const int mcnt = (k + 15) >> 4;
  const int kk3max = (k + 31) >> 5;
  const float* xb = xf + (size_t)b * 8192;

  if (lane == 0) outp[b] = (float)k;   // set_size

  // load P0 (R11-verified): p[mj][nr][q] = P[16nr+lc][16mj+4g+q]
  v4f p[4][4];
  {
    const float* P0 = outp + 8192 + (size_t)b * 8192;
#pragma unroll
    for (int mj = 0; mj < 4; ++mj)
#pragma unroll
      for (int nr = 0; nr < 4; ++nr)
        p[mj][nr] = *(const v4f*)&P0[((mj * 4 + nr) * 64 + lane) * 4];
  }

  // 20 Sinkhorn iterations, fully in-register, zero barriers
#pragma unroll 1
  for (int it = 0; it < 20; ++it) {
#pragma unroll
    for (int nr = 0; nr < 4; ++nr)
      if (nr < mcnt) {
        float s = 0.0f;
#pragma unroll
        for (int mj = 0; mj < 4; ++mj)
          if (mj < mcnt)
            s += (p[mj][nr][0] + p[mj][nr][1]) + (p[mj][nr][2] + p[mj][nr][3]);
        s += __shfl_xor(s, 16);
        s += __shfl_xor(s, 32);
        const float sc = frcp(s + 1e-30f);
#pragma unroll
        for (int mj = 0; mj < 4; ++mj)
          if (mj < mcnt) {
            p[mj][nr][0] *= sc; p[mj][nr][1] *= sc;
            p[mj][nr][2] *= sc; p[mj][nr][3] *= sc;
          }
      }
#pragma unroll
    for (int mj = 0; mj < 4; ++mj)
      if (mj < mcnt) {
#pragma unroll
        for (int q = 0; q < 4; ++q) {
          float c = 0.0f;
#pragma unroll
          for (int nr = 0; nr < 4; ++nr)
            if (nr < mcnt) c += p[mj][nr][q];
          c = red16_sum(c);
          const float sc = frcp(c + 1e-30f);
#pragma unroll
          for (int nr = 0; nr < 4; ++nr)
            if (nr < mcnt) p[mj][nr][q] *= sc;
        }
      }
  }

  // stage P^T: pth[(i>>3)*512 + j*8 + (i&7)], i = 16nr+lc, j = 16mj+4g+q
#pragma unroll
  for (int mj = 0; mj < 4; ++mj)
#pragma unroll
    for (int nr = 0; nr < 4; ++nr)
#pragma unroll
      for (int q = 0; q < 4; ++q)
        pth[((2 * nr + (lc >> 3)) * 64 + 16 * mj + 4 * g + q) * 8 + (lc & 7)] =
            (h16)p[mj][nr][q];
  asm volatile("s_waitcnt lgkmcnt(0)" ::: "memory");

  float* outb = outp + 8192 + (size_t)b * 8192;
#pragma unroll 1
  for (int c = 0; c < 4; ++c) {  // f-chunks of 32
    v4f acc3[4][2];
#pragma unroll
    for (int m = 0; m < 4; ++m)
#pragma unroll
      for (int nn = 0; nn < 2; ++nn) acc3[m][nn] = (v4f){0.f, 0.f, 0.f, 0.f};
#pragma unroll 1
    for (int kk = 0; kk < kk3max; ++kk) {
      h8 ap[4];
#pragma unroll
      for (int m = 0; m < 4; ++m)
        if (m < mcnt)
          ap[m] = *(const h8*)&pth[((4 * kk + g) * 64 + 16 * m + lc) * 8];
#pragma unroll
      for (int nn = 0; nn < 2; ++nn) {
        const int f = 16 * (2 * c + nn) + lc;
        v4f x0, x1;
#pragma unroll
        for (int e = 0; e < 4; ++e) x0[e] = xb[(kk * 32 + 8 * g + e) * 128 + f];
#pragma unroll
        for (int e = 0; e < 4; ++e) x1[e] = xb[(kk * 32 + 8 * g + 4 + e) * 128 + f];
        h8 bxx = cvt8(x0, x1);
#pragma unroll
        for (int m = 0; m < 4; ++m)
          if (m < mcnt)
            acc3[m][nn] = __builtin_amdgcn_mfma_f32_16x16x32_f16(ap[m], bxx, acc3[m][nn], 0, 0, 0);
      }
    }
#pragma unroll
    for (int m = 0; m < 4; ++m)
#pragma unroll
      for (int nn = 0; nn < 2; ++nn)
#pragma unroll
        for (int q = 0; q < 4; ++q)
          outb[(16 * m + 4 * g + q) * 128 + 16 * (2 * c + nn) + lc] = acc3[m][nn][q];
  }
}

extern "C" void kernel_launch(void* const* d_in, const int* in_sizes, int n_in,
                              void* d_out, int out_size, void* d_ws, size_t ws_size,
                              hipStream_t stream) {
  const float* xf = (const float*)d_in[0];
  const int* ssz = (const int*)d_in[1];
  // d_in[2] = maskB: unused (recomputed from set_size)
  const float* gn = (const float*)d_in[3];
  const float* W1 = (const float*)d_in[4];
  const float* b1 = (const float*)d_in[5];
  const float* W2 = (const float*)d_in[6];
  const float* b2 = (const float*)d_in[7];
  float* outp = (float*)d_out;

  const size_t ws_need = (size_t)(128 * 256 + 256 * 64) * sizeof(h16);  // 98304 B
  const bool use_ws = (d_ws != nullptr) && (ws_size >= ws_need);

  if (use_ws) {
    h16* w1s = (h16*)d_ws;             // [4][256][32] f16
    h16* w2s = w1s + 128 * 256;        // [8][64][32]  f16
    prep_w<<<192, 256, 0, stream>>>(W1, W2, w1s, w2s);
    mlp_init_wave<true><<<8192, 64, 0, stream>>>(xf, ssz, gn, b1, b2, w1s, w2s,
                                                 W1, W2, outp);
  } else {
    mlp_init_wave<false><<<8192, 64, 0, stream>>>(xf, ssz, gn, b1, b2,
                                                  (const h16*)nullptr,
                                                  (const h16*)nullptr,
                                                  W1, W2, outp);
  }
  sink_out<<<2048, 256, 0, stream>>>(xf, ssz, outp);
}

// Round 19
// 346.444 us; speedup vs baseline: 1.1398x; 1.1398x over previous
//
#include <hip/hip_runtime.h>
#include <hip/hip_bf16.h>

// PermutationGenerator: B=8192, N=64, D=128, LATENT=256, TEMP=0.1, 20 Sinkhorn iters.
// d_in (ALL f32): [0] padded [B][64][128], [1] set_size int32 [B], [2] maskB (UNUSED),
//       [3] gumbel [B][64][64], [4] W1 [128][256], [5] b1 [256],
//       [6] W2 [256][64], [7] b2 [64]
// d_out f32: [0:8192] set_size, then permuted [B][64][128].
//
// R19 = R16 verbatim (best verified config: 345.4us).
// Final architecture after 18 rounds:
//   prep_w:  W1/W2 -> f16, k-innermost coalesced layout (R12: 4x less L2 traffic).
//   A mlp_init (block-per-batch, ~214us): x -> swizzled f16 LDS arena ->
//     GEMM1 -> hh (XOR-swizzled) -> GEMM2 -> fused bias+gumbel+mask+rowmax+exp
//     -> P0 f32 stored in natural fragment order (clean 64B/thread writes).
//     gn prefetched in the low-pressure window, row+col gated. NO launch bound
//     (R13: VGPR caps below acc pressure => scratch spill, +370MB writes).
//   B sink_out (wave-per-batch, ~130us, ZERO barriers): P0 loaded with
//     load-side layout fix (16 full 64B lines/wave-instr), 20 Sinkhorn iters
//     fully in-register (shfl_xor row / DPP col), P^T staged to private
//     subtiled LDS (conflict-free b128), GEMM3, full-line stores. set_size
//     written by lane 0.
// Pinned-lever ledger: A ~213us across 4 structures (R13/R16/R17/R18);
// occupancy null (R4/R10); fusion regresses (R14 barrier-bound, R15
// VALU-redundant); multi-batch pipelining regresses (R4 lockstep, R9 spill).

typedef _Float16 h16;
typedef h16 h8 __attribute__((ext_vector_type(8)));
typedef __fp16 fp16x2 __attribute__((ext_vector_type(2)));
typedef float v4f __attribute__((ext_vector_type(4)));

template<int CTRL>
__device__ __forceinline__ float dppf(float x) {
  return __int_as_float(__builtin_amdgcn_update_dpp(
      0, __float_as_int(x), CTRL, 0xF, 0xF, true));
}
__device__ __forceinline__ float red16_sum(float x) {
  x += dppf<0xB1>(x);
  x += dppf<0x4E>(x);
  x += dppf<0x124>(x);
  x += dppf<0x128>(x);
  return x;
}
__device__ __forceinline__ float red16_max(float x) {
  x = fmaxf(x, dppf<0xB1>(x));
  x = fmaxf(x, dppf<0x4E>(x));
  x = fmaxf(x, dppf<0x124>(x));
  x = fmaxf(x, dppf<0x128>(x));
  return x;
}
__device__ __forceinline__ float frcp(float x) { return __builtin_amdgcn_rcpf(x); }
__device__ __forceinline__ h8 cvt8(v4f a, v4f b) {
  union { h8 v; fp16x2 p[4]; } u;
  u.p[0] = __builtin_amdgcn_cvt_pkrtz(a[0], a[1]);
  u.p[1] = __builtin_amdgcn_cvt_pkrtz(a[2], a[3]);
  u.p[2] = __builtin_amdgcn_cvt_pkrtz(b[0], b[1]);
  u.p[3] = __builtin_amdgcn_cvt_pkrtz(b[2], b[3]);
  return u.v;
}

// w1s[kk*8192 + col*32 + e] = W1[(kk*32+e)*256 + col]   (kk<4, col<256, e<32)
// w2s[kk*2048 + j*32 + e]   = W2[(kk*32+e)*64 + j]      (kk<8, j<64,  e<32)
__global__ __launch_bounds__(256) void prep_w(const float* __restrict__ W1,
                                              const float* __restrict__ W2,
                                              h16* __restrict__ w1s,
                                              h16* __restrict__ w2s) {
  int t = blockIdx.x * 256 + threadIdx.x;
  if (t < 128 * 256) {
    int row = t >> 8, col = t & 255;          // W1[row][col]
    int kk = row >> 5, e = row & 31;
    w1s[kk * 8192 + col * 32 + e] = (h16)W1[t];
  } else if (t < 128 * 256 + 256 * 64) {
    int t2 = t - 128 * 256;
    int row = t2 >> 6, j = t2 & 63;           // W2[row][j]
    int kk = row >> 5, e = row & 31;
    w2s[kk * 2048 + j * 32 + e] = (h16)W2[t2];
  }
}

// ================= Kernel A: MLP + Sinkhorn-init, store P0 (f32) =============
// LDS arena 32768: xh [64][128]swz -> hh [64][256]swz
template<bool WSF>
__global__ __launch_bounds__(256) void mlp_init(
    const float* __restrict__ xf,
    const int* __restrict__ ssz,
    const float* __restrict__ gn,
    const float* __restrict__ b1,
    const float* __restrict__ b2,
    const h16* __restrict__ w1s,   // coalesced layout
    const h16* __restrict__ w2s,
    const float* __restrict__ W1f,
    const float* __restrict__ W2f,
    float* __restrict__ outp) {
  __shared__ __align__(16) char smem[32768];

  const int tid = threadIdx.x, b = blockIdx.x;
  const int w = tid >> 6, lane = tid & 63, g = lane >> 4, lc = lane & 15;
  const int k = ssz[b];
  const int sr = tid >> 2, sseg = tid & 3;

  {  // stage x -> f16 LDS xh [64][128] swizzled: byte = r*256 + c*2 ^ ((r&7)<<4)
    const float* src = xf + (size_t)b * 8192 + sr * 128 + sseg * 32;
#pragma unroll
    for (int v = 0; v < 4; ++v) {
      const int byte = (sr * 256 + (sseg * 32 + v * 8) * 2) ^ ((sr & 7) << 4);
      *(h8*)(smem + byte) =
          cvt8(*(const v4f*)(src + v * 8), *(const v4f*)(src + v * 8 + 4));
    }
  }
  float b1v[4], b2v[4];
#pragma unroll
  for (int n = 0; n < 4; ++n) b1v[n] = b1[w * 64 + n * 16 + lc];
#pragma unroll
  for (int n = 0; n < 4; ++n) b2v[n] = b2[n * 16 + lc];
  __syncthreads();

  // GEMM1: h = relu(x@W1+b1); wave w -> cols [64w,64w+64)
  v4f acc1[4][4];
#pragma unroll
  for (int m = 0; m < 4; ++m)
#pragma unroll
    for (int n = 0; n < 4; ++n) acc1[m][n] = (v4f){0.f, 0.f, 0.f, 0.f};
#pragma unroll
  for (int kk = 0; kk < 4; ++kk) {
    h8 av[4], bv[4];
#pragma unroll
    for (int m = 0; m < 4; ++m) {
      const int row = lc + 16 * m;
      const int byte = (row * 256 + (kk * 32 + 8 * g) * 2) ^ ((row & 7) << 4);
      av[m] = *(const h8*)(smem + byte);
    }
#pragma unroll
    for (int n = 0; n < 4; ++n) {
      if (WSF) {
        bv[n] = *(const h8*)&w1s[kk * 8192 + (w * 64 + n * 16 + lc) * 32 + 8 * g];
      } else {
        h8 t;
#pragma unroll
        for (int e = 0; e < 8; ++e)
          t[e] = (h16)W1f[(kk * 32 + 8 * g + e) * 256 + (w * 64 + n * 16 + lc)];
        bv[n] = t;
      }
    }
#pragma unroll
    for (int m = 0; m < 4; ++m)
#pragma unroll
      for (int n = 0; n < 4; ++n)
        acc1[m][n] = __builtin_amdgcn_mfma_f32_16x16x32_f16(av[m], bv[n], acc1[m][n], 0, 0, 0);
  }

  // gn prefetch in LOW-pressure window; row- AND col-gated
  float gnr[4][4];
  if (16 * w < k) {
    const float* gnb = gn + (size_t)b * 4096;
#pragma unroll
    for (int i = 0; i < 4; ++i)
#pragma unroll
      for (int n = 0; n < 4; ++n)
        if (16 * n < k)
          gnr[i][n] = gnb[(16 * w + 4 * g + i) * 64 + 16 * n + lc];
  }

  __syncthreads();   // xh dead; arena becomes hh
  // hh store: byte = row*512 + col*2 ^ ((row&7)<<4)
#pragma unroll
  for (int m = 0; m < 4; ++m)
#pragma unroll
    for (int n = 0; n < 4; ++n)
#pragma unroll
      for (int q = 0; q < 4; ++q) {
        const int row = 16 * m + 4 * g + q;
        const int col = w * 64 + 16 * n + lc;
        const int byte = (row * 512 + col * 2) ^ ((row & 7) << 4);
        *(h16*)(smem + byte) = (h16)fmaxf(acc1[m][n][q] + b1v[n], 0.0f);
      }
  __syncthreads();

  // GEMM2: net rows [16w,16w+16); thread owns rows 16w+4g+i, cols 16n+lc
  v4f acc2[4];
#pragma unroll
  for (int n = 0; n < 4; ++n) acc2[n] = (v4f){0.f, 0.f, 0.f, 0.f};
  {
    const int row2 = 16 * w + lc;
#pragma unroll
    for (int kk = 0; kk < 8; ++kk) {
      const int byte = (row2 * 512 + (kk * 32 + 8 * g) * 2) ^ ((row2 & 7) << 4);
      h8 av = *(const h8*)(smem + byte);
#pragma unroll
      for (int n = 0; n < 4; ++n) {
        h8 bv;
        if (WSF) {
          bv = *(const h8*)&w2s[kk * 2048 + (n * 16 + lc) * 32 + 8 * g];
        } else {
          h8 t;
#pragma unroll
          for (int e = 0; e < 8; ++e)
            t[e] = (h16)W2f[(kk * 32 + 8 * g + e) * 64 + (n * 16 + lc)];
          bv = t;
        }
        acc2[n] = __builtin_amdgcn_mfma_f32_16x16x32_f16(av, bv, acc2[n], 0, 0, 0);
      }
    }
  }

  // init: P0 = exp2((la - rowmax)*10*log2e), masked -> 0
  float p[4][4];
#pragma unroll
  for (int i = 0; i < 4; ++i)
#pragma unroll
    for (int n = 0; n < 4; ++n) p[i][n] = 0.0f;
  if (16 * w < k) {
#pragma unroll
    for (int i = 0; i < 4; ++i) {
      const int row = 16 * w + 4 * g + i;
      float la[4];
#pragma unroll
      for (int n = 0; n < 4; ++n) {
        const int col = 16 * n + lc;
        const bool valid = (row < k) && (col < k);
        const float v = acc2[n][i] + b2v[n] + gnr[i][n];
        la[n] = valid ? v : -1e30f;
      }
      float m_ = fmaxf(fmaxf(la[0], la[1]), fmaxf(la[2], la[3]));
      m_ = red16_max(m_);
#pragma unroll
      for (int n = 0; n < 4; ++n)
        p[i][n] = (la[n] > -1e29f) ? exp2f((la[n] - m_) * 14.4269504089f) : 0.0f;
    }
  }

  // store P0 in natural fragment order (clean 64B/thread):
  //   P0[tid*16 + i*4 + n] = P[16w+4g+i][16n+lc]
  float* P0 = outp + 8192 + (size_t)b * 8192;
#pragma unroll
  for (int i = 0; i < 4; ++i) {
    v4f o;
#pragma unroll
    for (int n = 0; n < 4; ++n) o[n] = p[i][n];
    *(v4f*)&P0[tid * 16 + i * 4] = o;
  }
}

// ================= Kernel B: wave-per-batch Sinkhorn + GEMM3, ZERO barriers ==
// Per-wave private 8KB pth: P^T subtiled [i>>3][j][i&7] f16 (conflict-free b128)
__global__ __launch_bounds__(256, 4) void sink_out(
    const float* __restrict__ xf,
    const int* __restrict__ ssz,
    float* __restrict__ outp) {
  __shared__ h16 pth_all[4][4096];

  const int tid = threadIdx.x;
  const int w = tid >> 6, lane = tid & 63, g = lane >> 4, lc = lane & 15;
  h16* pth = pth_all[w];

  const int b = blockIdx.x * 4 + w;
  const int k = ssz[b];
  const int mcnt = (k + 15) >> 4;
  const int kk3max = (k + 31) >> 5;
  const float* xb = xf + (size_t)b * 8192;

  if (lane == 0) outp[b] = (float)k;   // set_size (folded write_ss)

  // load P0 from A's natural fragment order; layout fix on the load side:
  //   P[16nr+lc][16mj+4g+q] = P0[1024nr + 256(lc>>2) + 16(4g+q) + 4(lc&3) + mj]
  // Per (nr,q): one v4f, component mj. 16 fully-covered 64B lines per wave-load.
  v4f p[4][4];   // p[mj][nr][q]
  {
    const float* P0 = outp + 8192 + (size_t)b * 8192;
    const int base = 256 * (lc >> 2) + 4 * (lc & 3) + 64 * g;
#pragma unroll
    for (int nr = 0; nr < 4; ++nr)
#pragma unroll
      for (int q = 0; q < 4; ++q) {
        v4f t = *(const v4f*)&P0[1024 * nr + base + 16 * q];
        p[0][nr][q] = t[0]; p[1][nr][q] = t[1];
        p[2][nr][q] = t[2]; p[3][nr][q] = t[3];
      }
  }

  // 20 Sinkhorn iterations, fully in-register, zero barriers
#pragma unroll 1
  for (int it = 0; it < 20; ++it) {
#pragma unroll
    for (int nr = 0; nr < 4; ++nr)
      if (nr < mcnt) {
        float s = 0.0f;
#pragma unroll
        for (int mj = 0; mj < 4; ++mj)
          if (mj < mcnt)
            s += (p[mj][nr][0] + p[mj][nr][1]) + (p[mj][nr][2] + p[mj][nr][3]);
        s += __shfl_xor(s, 16);
        s += __shfl_xor(s, 32);
        const float sc = frcp(s + 1e-30f);
#pragma unroll
        for (int mj = 0; mj < 4; ++mj)
          if (mj < mcnt) {
            p[mj][nr][0] *= sc; p[mj][nr][1] *= sc;
            p[mj][nr][2] *= sc; p[mj][nr][3] *= sc;
          }
      }
#pragma unroll
    for (int mj = 0; mj < 4; ++mj)
      if (mj < mcnt) {
#pragma unroll
        for (int q = 0; q < 4; ++q) {
          float c = 0.0f;
#pragma unroll
          for (int nr = 0; nr < 4; ++nr)
            if (nr < mcnt) c += p[mj][nr][q];
          c = red16_sum(c);
          const float sc = frcp(c + 1e-30f);
#pragma unroll
          for (int nr = 0; nr < 4; ++nr)
            if (nr < mcnt) p[mj][nr][q] *= sc;
        }
      }
  }

  // stage P^T: pth[(i>>3)*512 + j*8 + (i&7)], i = 16nr+lc, j = 16mj+4g+q
#pragma unroll
  for (int mj = 0; mj < 4; ++mj)
#pragma unroll
    for (int nr = 0; nr < 4; ++nr)
#pragma unroll
      for (int q = 0; q < 4; ++q)
        pth[((2 * nr + (lc >> 3)) * 64 + 16 * mj + 4 * g + q) * 8 + (lc & 7)] =
            (h16)p[mj][nr][q];
  asm volatile("s_waitcnt lgkmcnt(0)" ::: "memory");

  float* outb = outp + 8192 + (size_t)b * 8192;
#pragma unroll 1
  for (int c = 0; c < 4; ++c) {  // f-chunks of 32
    v4f acc3[4][2];
#pragma unroll
    for (int m = 0; m < 4; ++m)
#pragma unroll
      for (int nn = 0; nn < 2; ++nn) acc3[m][nn] = (v4f){0.f, 0.f, 0.f, 0.f};
#pragma unroll 1
    for (int kk = 0; kk < kk3max; ++kk) {
      h8 ap[4];
#pragma unroll
      for (int m = 0; m < 4; ++m)
        if (m < mcnt)
          ap[m] = *(const h8*)&pth[((4 * kk + g) * 64 + 16 * m + lc) * 8];
#pragma unroll
      for (int nn = 0; nn < 2; ++nn) {
        const int f = 16 * (2 * c + nn) + lc;
        v4f x0, x1;
#pragma unroll
        for (int e = 0; e < 4; ++e) x0[e] = xb[(kk * 32 + 8 * g + e) * 128 + f];
#pragma unroll
        for (int e = 0; e < 4; ++e) x1[e] = xb[(kk * 32 + 8 * g + 4 + e) * 128 + f];
        h8 bxx = cvt8(x0, x1);
#pragma unroll
        for (int m = 0; m < 4; ++m)
          if (m < mcnt)
            acc3[m][nn] = __builtin_amdgcn_mfma_f32_16x16x32_f16(ap[m], bxx, acc3[m][nn], 0, 0, 0);
      }
    }
#pragma unroll
    for (int m = 0; m < 4; ++m)
#pragma unroll
      for (int nn = 0; nn < 2; ++nn)
#pragma unroll
        for (int q = 0; q < 4; ++q)
          outb[(16 * m + 4 * g + q) * 128 + 16 * (2 * c + nn) + lc] = acc3[m][nn][q];
  }
}

extern "C" void kernel_launch(void* const* d_in, const int* in_sizes, int n_in,
                              void* d_out, int out_size, void* d_ws, size_t ws_size,
                              hipStream_t stream) {
  const float* xf = (const float*)d_in[0];
  const int* ssz = (const int*)d_in[1];
  // d_in[2] = maskB: unused (recomputed from set_size)
  const float* gn = (const float*)d_in[3];
  const float* W1 = (const float*)d_in[4];
  const float* b1 = (const float*)d_in[5];
  const float* W2 = (const float*)d_in[6];
  const float* b2 = (const float*)d_in[7];
  float* outp = (float*)d_out;

  const size_t ws_need = (size_t)(128 * 256 + 256 * 64) * sizeof(h16);  // 98304 B
  const bool use_ws = (d_ws != nullptr) && (ws_size >= ws_need);

  if (use_ws) {
    h16* w1s = (h16*)d_ws;             // [4][256][32] f16
    h16* w2s = w1s + 128 * 256;        // [8][64][32]  f16
    prep_w<<<192, 256, 0, stream>>>(W1, W2, w1s, w2s);
    mlp_init<true><<<8192, 256, 0, stream>>>(xf, ssz, gn, b1, b2, w1s, w2s,
                                             W1, W2, outp);
  } else {
    mlp_init<false><<<8192, 256, 0, stream>>>(xf, ssz, gn, b1, b2,
                                              (const h16*)nullptr,
                                              (const h16*)nullptr,
                                              W1, W2, outp);
  }
  sink_out<<<2048, 256, 0, stream>>>(xf, ssz, outp);
}

// Round 20
// 343.274 us; speedup vs baseline: 1.1503x; 1.0092x over previous
//
#include <hip/hip_runtime.h>
#include <hip/hip_bf16.h>

// PermutationGenerator: B=8192, N=64, D=128, LATENT=256, TEMP=0.1, 20 Sinkhorn iters.
// d_in (ALL f32): [0] padded [B][64][128], [1] set_size int32 [B], [2] maskB (UNUSED),
//       [3] gumbel [B][64][64], [4] W1 [128][256], [5] b1 [256],
//       [6] W2 [256][64], [7] b2 [64]
// d_out f32: [0:8192] set_size, then permuted [B][64][128].
//
// R20 = R16/R19 with ONE change in A: GEMM1 computed as h^T = W1^T @ x^T
// (operand swap, R5/R6-HW-verified fragment math; waves partition the latent
// dim so MFMA count is unchanged). The D-frag then holds 4 CONSECUTIVE
// latents per thread -> hh store becomes 16x contiguous ds_write_b64 instead
// of 64x scalar ds_write_b16 + per-element swizzle math (~250 VALU + 48 LDS
// ops saved per thread; the largest serial block in A, whose busiest pipe is
// VALU at 20.8%). GEMM2 and all downstream are byte-identical (same hh
// layout+swizzle formula on both sides).
// Ledger: A ~213us across 4 structures; occupancy null (R4/R10); fusion
// regresses (R14/R15); multi-batch pipelining regresses (R4/R9); no launch
// bound (R13 spill).

typedef _Float16 h16;
typedef h16 h8 __attribute__((ext_vector_type(8)));
typedef h16 h4 __attribute__((ext_vector_type(4)));
typedef __fp16 fp16x2 __attribute__((ext_vector_type(2)));
typedef float v4f __attribute__((ext_vector_type(4)));

template<int CTRL>
__device__ __forceinline__ float dppf(float x) {
  return __int_as_float(__builtin_amdgcn_update_dpp(
      0, __float_as_int(x), CTRL, 0xF, 0xF, true));
}
__device__ __forceinline__ float red16_sum(float x) {
  x += dppf<0xB1>(x);
  x += dppf<0x4E>(x);
  x += dppf<0x124>(x);
  x += dppf<0x128>(x);
  return x;
}
__device__ __forceinline__ float red16_max(float x) {
  x = fmaxf(x, dppf<0xB1>(x));
  x = fmaxf(x, dppf<0x4E>(x));
  x = fmaxf(x, dppf<0x124>(x));
  x = fmaxf(x, dppf<0x128>(x));
  return x;
}
__device__ __forceinline__ float frcp(float x) { return __builtin_amdgcn_rcpf(x); }
__device__ __forceinline__ h8 cvt8(v4f a, v4f b) {
  union { h8 v; fp16x2 p[4]; } u;
  u.p[0] = __builtin_amdgcn_cvt_pkrtz(a[0], a[1]);
  u.p[1] = __builtin_amdgcn_cvt_pkrtz(a[2], a[3]);
  u.p[2] = __builtin_amdgcn_cvt_pkrtz(b[0], b[1]);
  u.p[3] = __builtin_amdgcn_cvt_pkrtz(b[2], b[3]);
  return u.v;
}

// w1s[kk*8192 + col*32 + e] = W1[(kk*32+e)*256 + col]   (kk<4, col<256, e<32)
// w2s[kk*2048 + j*32 + e]   = W2[(kk*32+e)*64 + j]      (kk<8, j<64,  e<32)
__global__ __launch_bounds__(256) void prep_w(const float* __restrict__ W1,
                                              const float* __restrict__ W2,
                                              h16* __restrict__ w1s,
                                              h16* __restrict__ w2s) {
  int t = blockIdx.x * 256 + threadIdx.x;
  if (t < 128 * 256) {
    int row = t >> 8, col = t & 255;          // W1[row][col]
    int kk = row >> 5, e = row & 31;
    w1s[kk * 8192 + col * 32 + e] = (h16)W1[t];
  } else if (t < 128 * 256 + 256 * 64) {
    int t2 = t - 128 * 256;
    int row = t2 >> 6, j = t2 & 63;           // W2[row][j]
    int kk = row >> 5, e = row & 31;
    w2s[kk * 2048 + j * 32 + e] = (h16)W2[t2];
  }
}

// ================= Kernel A: MLP + Sinkhorn-init, store P0 (f32) =============
// LDS arena 32768: xh [64][128]swz -> hh [64][256]swz
template<bool WSF>
__global__ __launch_bounds__(256) void mlp_init(
    const float* __restrict__ xf,
    const int* __restrict__ ssz,
    const float* __restrict__ gn,
    const float* __restrict__ b1,
    const float* __restrict__ b2,
    const h16* __restrict__ w1s,   // coalesced layout (== W1^T row-contig)
    const h16* __restrict__ w2s,
    const float* __restrict__ W1f,
    const float* __restrict__ W2f,
    float* __restrict__ outp) {
  __shared__ __align__(16) char smem[32768];

  const int tid = threadIdx.x, b = blockIdx.x;
  const int w = tid >> 6, lane = tid & 63, g = lane >> 4, lc = lane & 15;
  const int k = ssz[b];
  const int sr = tid >> 2, sseg = tid & 3;

  {  // stage x -> f16 LDS xh [64][128] swizzled: byte = r*256 + c*2 ^ ((r&7)<<4)
    const float* src = xf + (size_t)b * 8192 + sr * 128 + sseg * 32;
#pragma unroll
    for (int v = 0; v < 4; ++v) {
      const int byte = (sr * 256 + (sseg * 32 + v * 8) * 2) ^ ((sr & 7) << 4);
      *(h8*)(smem + byte) =
          cvt8(*(const v4f*)(src + v * 8), *(const v4f*)(src + v * 8 + 4));
    }
  }
  // b1 fragments for h^T D-frag: b1t[t][q] = b1[64w + 16t + 4g + q]
  v4f b1t[4];
#pragma unroll
  for (int t = 0; t < 4; ++t) b1t[t] = *(const v4f*)&b1[w * 64 + t * 16 + 4 * g];
  float b2v[4];
#pragma unroll
  for (int n = 0; n < 4; ++n) b2v[n] = b2[n * 16 + lc];
  __syncthreads();

  // GEMM1': h^T = W1^T @ x^T; wave w -> latents [64w, 64w+64)
  // accT[t][nr][q] = h^T[64w+16t+4g+q][16nr+lc]  (R5/R6-verified frag math)
  v4f accT[4][4];
#pragma unroll
  for (int t = 0; t < 4; ++t)
#pragma unroll
    for (int nr = 0; nr < 4; ++nr) accT[t][nr] = (v4f){0.f, 0.f, 0.f, 0.f};
#pragma unroll
  for (int kk = 0; kk < 4; ++kk) {
    h8 bx[4], aw[4];
#pragma unroll
    for (int nr = 0; nr < 4; ++nr) {  // B-op: x rows (same xh reads as before)
      const int row = lc + 16 * nr;
      const int byte = (row * 256 + (kk * 32 + 8 * g) * 2) ^ ((row & 7) << 4);
      bx[nr] = *(const h8*)(smem + byte);
    }
#pragma unroll
    for (int t = 0; t < 4; ++t) {     // A-op: W1^T rows lat (coalesced)
      if (WSF) {
        aw[t] = *(const h8*)&w1s[kk * 8192 + (w * 64 + t * 16 + lc) * 32 + 8 * g];
      } else {
        h8 tt;
#pragma unroll
        for (int e = 0; e < 8; ++e)
          tt[e] = (h16)W1f[(kk * 32 + 8 * g + e) * 256 + (w * 64 + t * 16 + lc)];
        aw[t] = tt;
      }
    }
#pragma unroll
    for (int t = 0; t < 4; ++t)
#pragma unroll
      for (int nr = 0; nr < 4; ++nr)
        accT[t][nr] = __builtin_amdgcn_mfma_f32_16x16x32_f16(aw[t], bx[nr], accT[t][nr], 0, 0, 0);
  }

  // gn prefetch in LOW-pressure window; row- AND col-gated
  float gnr[4][4];
  if (16 * w < k) {
    const float* gnb = gn + (size_t)b * 4096;
#pragma unroll
    for (int i = 0; i < 4; ++i)
#pragma unroll
      for (int n = 0; n < 4; ++n)
        if (16 * n < k)
          gnr[i][n] = gnb[(16 * w + 4 * g + i) * 64 + 16 * n + lc];
  }

  __syncthreads();   // xh dead; arena becomes hh
  // hh store: 16x contiguous ds_write_b64 (4 consecutive latents per thread)
  //   hh[row][col..col+3], row = 16nr+lc, col = 64w+16t+4g; same swizzle formula
#pragma unroll
  for (int t = 0; t < 4; ++t)
#pragma unroll
    for (int nr = 0; nr < 4; ++nr) {
      h4 hv;
#pragma unroll
      for (int q = 0; q < 4; ++q)
        hv[q] = (h16)fmaxf(accT[t][nr][q] + b1t[t][q], 0.0f);
      const int row = 16 * nr + lc;
      const int col = w * 64 + 16 * t + 4 * g;
      const int byte = (row * 512 + col * 2) ^ ((row & 7) << 4);
      *(h4*)(smem + byte) = hv;
    }
  __syncthreads();

  // GEMM2: net rows [16w,16w+16); thread owns rows 16w+4g+i, cols 16n+lc
  // (byte-identical to R16/R19: same hh layout + swizzle on the read side)
  v4f acc2[4];
#pragma unroll
  for (int n = 0; n < 4; ++n) acc2[n] = (v4f){0.f, 0.f, 0.f, 0.f};
  {
    const int row2 = 16 * w + lc;
#pragma unroll
    for (int kk = 0; kk < 8; ++kk) {
      const int byte = (row2 * 512 + (kk * 32 + 8 * g) * 2) ^ ((row2 & 7) << 4);
      h8 av = *(const h8*)(smem + byte);
#pragma unroll
      for (int n = 0; n < 4; ++n) {
        h8 bv;
        if (WSF) {
          bv = *(const h8*)&w2s[kk * 2048 + (n * 16 + lc) * 32 + 8 * g];
        } else {
          h8 t;
#pragma unroll
          for (int e = 0; e < 8; ++e)
            t[e] = (h16)W2f[(kk * 32 + 8 * g + e) * 64 + (n * 16 + lc)];
          bv = t;
        }
        acc2[n] = __builtin_amdgcn_mfma_f32_16x16x32_f16(av, bv, acc2[n], 0, 0, 0);
      }
    }
  }

  // init: P0 = exp2((la - rowmax)*10*log2e), masked -> 0
  float p[4][4];
#pragma unroll
  for (int i = 0; i < 4; ++i)
#pragma unroll
    for (int n = 0; n < 4; ++n) p[i][n] = 0.0f;
  if (16 * w < k) {
#pragma unroll
    for (int i = 0; i < 4; ++i) {
      const int row = 16 * w + 4 * g + i;
      float la[4];
#pragma unroll
      for (int n = 0; n < 4; ++n) {
        const int col = 16 * n + lc;
        const bool valid = (row < k) && (col < k);
        const float v = acc2[n][i] + b2v[n] + gnr[i][n];
        la[n] = valid ? v : -1e30f;
      }
      float m_ = fmaxf(fmaxf(la[0], la[1]), fmaxf(la[2], la[3]));
      m_ = red16_max(m_);
#pragma unroll
      for (int n = 0; n < 4; ++n)
        p[i][n] = (la[n] > -1e29f) ? exp2f((la[n] - m_) * 14.4269504089f) : 0.0f;
    }
  }

  // store P0 in natural fragment order (clean 64B/thread):
  //   P0[tid*16 + i*4 + n] = P[16w+4g+i][16n+lc]
  float* P0 = outp + 8192 + (size_t)b * 8192;
#pragma unroll
  for (int i = 0; i < 4; ++i) {
    v4f o;
#pragma unroll
    for (int n = 0; n < 4; ++n) o[n] = p[i][n];
    *(v4f*)&P0[tid * 16 + i * 4] = o;
  }
}

// ================= Kernel B: wave-per-batch Sinkhorn + GEMM3, ZERO barriers ==
// Per-wave private 8KB pth: P^T subtiled [i>>3][j][i&7] f16 (conflict-free b128)
__global__ __launch_bounds__(256, 4) void sink_out(
    const float* __restrict__ xf,
    const int* __restrict__ ssz,
    float* __restrict__ outp) {
  __shared__ h16 pth_all[4][4096];

  const int tid = threadIdx.x;
  const int w = tid >> 6, lane = tid & 63, g = lane >> 4, lc = lane & 15;
  h16* pth = pth_all[w];

  const int b = blockIdx.x * 4 + w;
  const int k = ssz[b];
  const int mcnt = (k + 15) >> 4;
  const int kk3max = (k + 31) >> 5;
  const float* xb = xf + (size_t)b * 8192;

  if (lane == 0) outp[b] = (float)k;   // set_size (folded write_ss)

  // load P0 from A's natural fragment order; layout fix on the load side:
  //   P[16nr+lc][16mj+4g+q] = P0[1024nr + 256(lc>>2) + 16(4g+q) + 4(lc&3) + mj]
  v4f p[4][4];   // p[mj][nr][q]
  {
    const float* P0 = outp + 8192 + (size_t)b * 8192;
    const int base = 256 * (lc >> 2) + 4 * (lc & 3) + 64 * g;
#pragma unroll
    for (int nr = 0; nr < 4; ++nr)
#pragma unroll
      for (int q = 0; q < 4; ++q) {
        v4f t = *(const v4f*)&P0[1024 * nr + base + 16 * q];
        p[0][nr][q] = t[0]; p[1][nr][q] = t[1];
        p[2][nr][q] = t[2]; p[3][nr][q] = t[3];
      }
  }

  // 20 Sinkhorn iterations, fully in-register, zero barriers
#pragma unroll 1
  for (int it = 0; it < 20; ++it) {
#pragma unroll
    for (int nr = 0; nr < 4; ++nr)
      if (nr < mcnt) {
        float s = 0.0f;
#pragma unroll
        for (int mj = 0; mj < 4; ++mj)
          if (mj < mcnt)
            s += (p[mj][nr][0] + p[mj][nr][1]) + (p[mj][nr][2] + p[mj][nr][3]);
        s += __shfl_xor(s, 16);
        s += __shfl_xor(s, 32);
        const float sc = frcp(s + 1e-30f);
#pragma unroll
        for (int mj = 0; mj < 4; ++mj)
          if (mj < mcnt) {
            p[mj][nr][0] *= sc; p[mj][nr][1] *= sc;
            p[mj][nr][2] *= sc; p[mj][nr][3] *= sc;
          }
      }
#pragma unroll
    for (int mj = 0; mj < 4; ++mj)
      if (mj < mcnt) {
#pragma unroll
        for (int q = 0; q < 4; ++q) {
          float c = 0.0f;
#pragma unroll
          for (int nr = 0; nr < 4; ++nr)
            if (nr < mcnt) c += p[mj][nr][q];
          c = red16_sum(c);
          const float sc = frcp(c + 1e-30f);
#pragma unroll
          for (int nr = 0; nr < 4; ++nr)
            if (nr < mcnt) p[mj][nr][q] *= sc;
        }
      }
  }

  // stage P^T: pth[(i>>3)*512 + j*8 + (i&7)], i = 16nr+lc, j = 16mj+4g+q
#pragma unroll
  for (int mj = 0; mj < 4; ++mj)
#pragma unroll
    for (int nr = 0; nr < 4; ++nr)
#pragma unroll
      for (int q = 0; q < 4; ++q)
        pth[((2 * nr + (lc >> 3)) * 64 + 16 * mj + 4 * g + q) * 8 + (lc & 7)] =
            (h16)p[mj][nr][q];
  asm volatile("s_waitcnt lgkmcnt(0)" ::: "memory");

  float* outb = outp + 8192 + (size_t)b * 8192;
#pragma unroll 1
  for (int c = 0; c < 4; ++c) {  // f-chunks of 32
    v4f acc3[4][2];
#pragma unroll
    for (int m = 0; m < 4; ++m)
#pragma unroll
      for (int nn = 0; nn < 2; ++nn) acc3[m][nn] = (v4f){0.f, 0.f, 0.f, 0.f};
#pragma unroll 1
    for (int kk = 0; kk < kk3max; ++kk) {
      h8 ap[4];
#pragma unroll
      for (int m = 0; m < 4; ++m)
        if (m < mcnt)
          ap[m] = *(const h8*)&pth[((4 * kk + g) * 64 + 16 * m + lc) * 8];
#pragma unroll
      for (int nn = 0; nn < 2; ++nn) {
        const int f = 16 * (2 * c + nn) + lc;
        v4f x0, x1;
#pragma unroll
        for (int e = 0; e < 4; ++e) x0[e] = xb[(kk * 32 + 8 * g + e) * 128 + f];
#pragma unroll
        for (int e = 0; e < 4; ++e) x1[e] = xb[(kk * 32 + 8 * g + 4 + e) * 128 + f];
        h8 bxx = cvt8(x0, x1);
#pragma unroll
        for (int m = 0; m < 4; ++m)
          if (m < mcnt)
            acc3[m][nn] = __builtin_amdgcn_mfma_f32_16x16x32_f16(ap[m], bxx, acc3[m][nn], 0, 0, 0);
      }
    }
#pragma unroll
    for (int m = 0; m < 4; ++m)
#pragma unroll
      for (int nn = 0; nn < 2; ++nn)
#pragma unroll
        for (int q = 0; q < 4; ++q)
          outb[(16 * m + 4 * g + q) * 128 + 16 * (2 * c + nn) + lc] = acc3[m][nn][q];
  }
}

extern "C" void kernel_launch(void* const* d_in, const int* in_sizes, int n_in,
                              void* d_out, int out_size, void* d_ws, size_t ws_size,
                              hipStream_t stream) {
  const float* xf = (const float*)d_in[0];
  const int* ssz = (const int*)d_in[1];
  // d_in[2] = maskB: unused (recomputed from set_size)
  const float* gn = (const float*)d_in[3];
  const float* W1 = (const float*)d_in[4];
  const float* b1 = (const float*)d_in[5];
  const float* W2 = (const float*)d_in[6];
  const float* b2 = (const float*)d_in[7];
  float* outp = (float*)d_out;

  const size_t ws_need = (size_t)(128 * 256 + 256 * 64) * sizeof(h16);  // 98304 B
  const bool use_ws = (d_ws != nullptr) && (ws_size >= ws_need);

  if (use_ws) {
    h16* w1s = (h16*)d_ws;             // [4][256][32] f16
    h16* w2s = w1s + 128 * 256;        // [8][64][32]  f16
    prep_w<<<192, 256, 0, stream>>>(W1, W2, w1s, w2s);
    mlp_init<true><<<8192, 256, 0, stream>>>(xf, ssz, gn, b1, b2, w1s, w2s,
                                             W1, W2, outp);
  } else {
    mlp_init<false><<<8192, 256, 0, stream>>>(xf, ssz, gn, b1, b2,
                                              (const h16*)nullptr,
                                              (const h16*)nullptr,
                                              W1, W2, outp);
  }
  sink_out<<<2048, 256, 0, stream>>>(xf, ssz, outp);
}